// Round 16
// baseline (602.635 us; speedup 1.0000x reference)
//
#include <hip/hip_runtime.h>
#include <hip/hip_fp16.h>
#include <math.h>

// ---------------------------------------------------------------------------
// GAT pipeline: 3x (GEMM16+alpha fused -> CSR segment-softmax aggregate) + FC
// R23: deeper prologue fusion. R22's fused kernel (114us) lost atomic MLP:
//      grid-stride unroll-1 serialized each thread's atomics on the returned
//      value (vs R21's unroll-4 = 4 in flight). Also cvt (~15-20us) still
//      serialized before it. Now ONE launch, three roles:
//        [0,CNTB)            count_rank, unroll-4 batched atomics (R21 MLP)
//        [CNTB,CNTB+1024)    gemm1 reading FP32 x directly (inline cvt) and
//                            staging w1 fp32->fp16 in LDS (x16/wh1 deleted)
//        [.., +192)          cvtw for w2/w3/fcwT (needed much later)
//      Count blocks first -> immediate residency for the atomic critical
//      path; gemm1+cvtw hide inside it. Layers 2/3, aggregates, MFMA FC
//      unchanged (584us proven).
// ---------------------------------------------------------------------------

typedef _Float16 h2_t __attribute__((ext_vector_type(2)));
typedef _Float16 f16x8 __attribute__((ext_vector_type(8)));
typedef float f32x4 __attribute__((ext_vector_type(4)));

__device__ __forceinline__ h2_t as_h2(unsigned int u) {
    union { unsigned int u; h2_t h; } x; x.u = u; return x.h;
}

__device__ __forceinline__ unsigned int pack2(float a, float b) {
    union { h2_t h; unsigned int u; } x;
    x.h[0] = (_Float16)a; x.h[1] = (_Float16)b;
    return x.u;
}

__device__ __forceinline__ float fdot2(h2_t a, h2_t b, float c) {
#if __has_builtin(__builtin_amdgcn_fdot2)
    return __builtin_amdgcn_fdot2(a, b, c, false);
#else
    return c + (float)a[0] * (float)b[0] + (float)a[1] * (float)b[1];
#endif
}

// ---------------------------------------------------------------------------
// Fused layer-1 launch: count_rank + gemm1(fp32 in, inline W cvt) + cvtw.
// ---------------------------------------------------------------------------
__global__ __launch_bounds__(256) void layer1_fused_kernel(
        const float* __restrict__ x,      // [N][128] fp32
        const float* __restrict__ w1,     // [128][64] fp32
        __half* __restrict__ out,         // [N][64] fp16
        const float* __restrict__ a_src,  // [64]
        const float* __restrict__ a_dst,  // [64]
        float* __restrict__ alpS,
        float* __restrict__ alpD,
        int N,
        const int* __restrict__ ei, int E,
        int* __restrict__ cnt, int* __restrict__ rank,
        const float* __restrict__ w2, const float* __restrict__ w3,
        const float* __restrict__ fcw,
        __half* __restrict__ o2, __half* __restrict__ o3,
        __half* __restrict__ o4T,
        int CNTB, int GEMMB) {
    __shared__ uint2 wlds[32 * 64];   // 16 KB (K4=32, CHUNK=64)

    if (blockIdx.x < CNTB) {
        // ---- role A: count_rank, 4 batched atomics/thread (R21 MLP) ----
        const int Etot = E + N;
        const int T = CNTB * 256;
        int e = blockIdx.x * 256 + threadIdx.x;
#pragma unroll 4
        for (int u = 0; u < 4; ++u, e += T) {
            if (e < Etot) {
                int dst = (e < E) ? ei[E + e] : (e - E);   // self-loops appended
                rank[e] = atomicAdd(&cnt[dst], 1);
            }
        }
        return;
    }
    if (blockIdx.x >= CNTB + GEMMB) {
        // ---- role C: cvtw for w2, w3, fcwT (49152 elems) ----
        int i = (blockIdx.x - CNTB - GEMMB) * 256 + threadIdx.x;
        if (i < 8192)       o2[i]         = (__half)w2[i];
        else if (i < 16384) o3[i - 8192]  = (__half)w3[i - 8192];
        else if (i < 49152) {
            int j = i - 16384;              // fcw is [64][512] row-major
            int k = j >> 9, c = j & 511;
            o4T[c * 64 + k] = (__half)fcw[j];   // -> [512][64] transposed
        }
        return;
    }

    // ---- role B: layer-1 GEMM, fp32 x, inline W conversion ----
    const int bid = blockIdx.x - CNTB;
    for (int idx = threadIdx.x; idx < 32 * 64; idx += 256) {
        int k4 = idx >> 6, c = idx & 63;
        const float* wp = w1 + (size_t)(4 * k4) * 64 + c;
        uint2 v;
        v.x = pack2(wp[0], wp[64]);
        v.y = pack2(wp[128], wp[192]);
        wlds[idx] = v;
    }
    __syncthreads();

    const int wid  = threadIdx.x >> 6;
    const int lane = threadIdx.x & 63;
    const float aSv = a_src[lane];
    const float aDv = a_dst[lane];

    const int groups = (N + 7) / 8;
    for (int g = bid * 4 + wid; g < groups; g += GEMMB * 4) {
        const int n0 = g * 8;
        const bool full = (n0 + 8 <= N);

        float acc[8];
#pragma unroll
        for (int r = 0; r < 8; ++r) acc[r] = 0.0f;

        const float4* xp = (const float4*)(x + (size_t)n0 * 128);

        if (full) {
#pragma unroll 2
            for (int k4 = 0; k4 < 32; ++k4) {
                float4 xr[8];
#pragma unroll
                for (int r = 0; r < 8; ++r) xr[r] = xp[r * 32 + k4];
                uint2 wv = wlds[k4 * 64 + lane];
#pragma unroll
                for (int r = 0; r < 8; ++r) {
                    h2_t lo, hi;
                    lo[0] = (_Float16)xr[r].x; lo[1] = (_Float16)xr[r].y;
                    hi[0] = (_Float16)xr[r].z; hi[1] = (_Float16)xr[r].w;
                    acc[r] = fdot2(lo, as_h2(wv.x), acc[r]);
                    acc[r] = fdot2(hi, as_h2(wv.y), acc[r]);
                }
            }
        } else {
#pragma unroll 1
            for (int k4 = 0; k4 < 32; ++k4) {
                uint2 wv = wlds[k4 * 64 + lane];
#pragma unroll 1
                for (int r = 0; r < 8; ++r) {
                    if (n0 + r >= N) break;
                    float4 xr = xp[r * 32 + k4];
                    h2_t lo, hi;
                    lo[0] = (_Float16)xr.x; lo[1] = (_Float16)xr.y;
                    hi[0] = (_Float16)xr.z; hi[1] = (_Float16)xr.w;
                    acc[r] = fdot2(lo, as_h2(wv.x), acc[r]);
                    acc[r] = fdot2(hi, as_h2(wv.y), acc[r]);
                }
            }
        }

#pragma unroll
        for (int r = 0; r < 8; ++r) {
            if (!full && n0 + r >= N) break;
            const int n = n0 + r;
            out[(size_t)n * 64 + lane] = (__half)acc[r];

            float ps = acc[r] * aSv, pd = acc[r] * aDv;
            for (int mm = 16; mm >= 1; mm >>= 1) {
                ps += __shfl_xor(ps, mm, 64);
                pd += __shfl_xor(pd, mm, 64);
            }
            if ((lane & 31) == 0) {
                int idx = n * 2 + (lane >> 5);
                alpS[idx] = ps; alpD[idx] = pd;
            }
        }
    }
}

// ---------------------------------------------------------------------------
// Parallel scan, 3 phases. NB=256 blocks, chunk = ceil(N/NB) <= 256.
// ---------------------------------------------------------------------------
#define SCAN_NB 256

__global__ __launch_bounds__(256) void scanA_kernel(const int* __restrict__ cnt,
                                                    int N, int* __restrict__ bsum) {
    __shared__ int red[256];
    const int chunk = (N + SCAN_NB - 1) / SCAN_NB;
    const int lo = blockIdx.x * chunk;
    const int len = min(N - lo, chunk);
    int s = 0;
    for (int i = threadIdx.x; i < len; i += 256) s += cnt[lo + i];
    red[threadIdx.x] = s;
    __syncthreads();
    for (int off = 128; off >= 1; off >>= 1) {
        if (threadIdx.x < off) red[threadIdx.x] += red[threadIdx.x + off];
        __syncthreads();
    }
    if (threadIdx.x == 0) bsum[blockIdx.x] = red[0];
}

__global__ __launch_bounds__(256) void scanB_kernel(int* __restrict__ bsum,
                                                    int* __restrict__ bbase) {
    __shared__ int s[256];
    int v = bsum[threadIdx.x];
    s[threadIdx.x] = v;
    __syncthreads();
    for (int off = 1; off < 256; off <<= 1) {
        int t = (threadIdx.x >= off) ? s[threadIdx.x - off] : 0;
        __syncthreads();
        s[threadIdx.x] += t;
        __syncthreads();
    }
    bbase[threadIdx.x] = s[threadIdx.x] - v;   // exclusive
}

__global__ __launch_bounds__(256) void scanC_kernel(const int* __restrict__ cnt,
                                                    int N, int Etot,
                                                    const int* __restrict__ bbase,
                                                    int* __restrict__ row_ptr) {
    __shared__ int s[256];
    const int chunk = (N + SCAN_NB - 1) / SCAN_NB;
    const int lo = blockIdx.x * chunk;
    const int len = min(N - lo, chunk);
    const int t = threadIdx.x;
    int v = (t < len) ? cnt[lo + t] : 0;
    s[t] = v;
    __syncthreads();
    for (int off = 1; off < 256; off <<= 1) {
        int u = (t >= off) ? s[t - off] : 0;
        __syncthreads();
        s[t] += u;
        __syncthreads();
    }
    if (t < len) row_ptr[lo + t] = bbase[blockIdx.x] + s[t] - v;
    if (blockIdx.x == 0 && t == 0) row_ptr[N] = Etot;
}

// pass 3: pos = row_ptr[dst] + rank[e]; atomic-free scattered store.
__global__ void scatter_kernel(const int* __restrict__ ei, int E, int N,
                               const int* __restrict__ row_ptr,
                               const int* __restrict__ rank,
                               int* __restrict__ csr_src) {
    const int Etot = E + N;
    const int T = gridDim.x * blockDim.x;
    int e = blockIdx.x * blockDim.x + threadIdx.x;
#pragma unroll 4
    for (int u = 0; u < 4; ++u, e += T) {
        if (e < Etot) {
            int src, dst;
            if (e < E) { src = ei[e]; dst = ei[E + e]; }
            else       { src = e - E; dst = e - E; }
            csr_src[row_ptr[dst] + rank[e]] = src;
        }
    }
}

// ---------------------------------------------------------------------------
// Layer GEMM (layers 2/3), fp16 in/W, fp32 acc via fdot2, fp16 out, fused
// alpha (R18-proven). 256 thr / 4 waves, 16KB LDS W tile, RB=8, ping-pong,
// unroll 2, grid 2048 = 8 blocks/CU.
// ALPHA: 2=(H2,C64,PL2)  3=(H1,C64)
// ---------------------------------------------------------------------------
template <int K, int CHUNK, int RB, int ALPHA>
__global__ __launch_bounds__(256) void gemm16_kernel(
        const __half* __restrict__ in,
        const __half* __restrict__ Wh,
        __half* __restrict__ out,
        const float* __restrict__ a_src,
        const float* __restrict__ a_dst,
        float* __restrict__ alpS,
        float* __restrict__ alpD,
        int N, int M) {
    constexpr int PL = CHUNK / 64;
    constexpr int K4 = K / 4;
    __shared__ uint2 wlds[K4 * CHUNK];   // 16 KB
    const unsigned short* wsrc = (const unsigned short*)Wh;
    for (int idx = threadIdx.x; idx < K4 * CHUNK; idx += 256) {
        int k4 = idx / CHUNK, c = idx % CHUNK;
        const unsigned short* wp = wsrc + (size_t)(4 * k4) * M + c;
        uint2 v;
        v.x = (unsigned int)wp[0]     | ((unsigned int)wp[M] << 16);
        v.y = (unsigned int)wp[2 * M] | ((unsigned int)wp[3 * M] << 16);
        wlds[idx] = v;
    }
    __syncthreads();

    const int wid  = threadIdx.x >> 6;
    const int lane = threadIdx.x & 63;

    float aSv[PL], aDv[PL];
#pragma unroll
    for (int j = 0; j < PL; ++j) {
        aSv[j] = a_src[lane + 64 * j];
        aDv[j] = a_dst[lane + 64 * j];
    }

    const int groups = (N + RB - 1) / RB;
    for (int g = blockIdx.x * 4 + wid; g < groups; g += gridDim.x * 4) {
        const int n0 = g * RB;
        const bool full = (n0 + RB <= N);

        float acc[RB][PL];
#pragma unroll
        for (int r = 0; r < RB; ++r)
#pragma unroll
            for (int j = 0; j < PL; ++j) acc[r][j] = 0.0f;

        const uint2* xp = (const uint2*)(in + (size_t)n0 * K);

        if (full) {
            uint2 xv[RB], xn[RB];
#pragma unroll
            for (int r = 0; r < RB; ++r) xv[r] = xp[r * K4];
#pragma unroll 2
            for (int k4 = 0; k4 < K4; ++k4) {
                if (k4 + 1 < K4) {
#pragma unroll
                    for (int r = 0; r < RB; ++r)
                        xn[r] = xp[r * K4 + k4 + 1];
                }
#pragma unroll
                for (int j = 0; j < PL; ++j) {
                    uint2 wv = wlds[k4 * CHUNK + lane + 64 * j];
#pragma unroll
                    for (int r = 0; r < RB; ++r) {
                        acc[r][j] = fdot2(as_h2(xv[r].x), as_h2(wv.x), acc[r][j]);
                        acc[r][j] = fdot2(as_h2(xv[r].y), as_h2(wv.y), acc[r][j]);
                    }
                }
                if (k4 + 1 < K4) {
#pragma unroll
                    for (int r = 0; r < RB; ++r) xv[r] = xn[r];
                }
            }
        } else {
#pragma unroll 1
            for (int k4 = 0; k4 < K4; ++k4) {
#pragma unroll 1
                for (int r = 0; r < RB; ++r) {
                    if (n0 + r >= N) break;
                    uint2 xr = xp[(size_t)r * K4 + k4];
#pragma unroll
                    for (int j = 0; j < PL; ++j) {
                        uint2 wv = wlds[k4 * CHUNK + lane + 64 * j];
                        acc[r][j] = fdot2(as_h2(xr.x), as_h2(wv.x), acc[r][j]);
                        acc[r][j] = fdot2(as_h2(xr.y), as_h2(wv.y), acc[r][j]);
                    }
                }
            }
        }

#pragma unroll
        for (int r = 0; r < RB; ++r) {
            if (!full && n0 + r >= N) break;
            const int n = n0 + r;
#pragma unroll
            for (int j = 0; j < PL; ++j)
                out[(size_t)n * M + lane + 64 * j] = (__half)acc[r][j];

            float ps[PL], pd[PL];
#pragma unroll
            for (int j = 0; j < PL; ++j) { ps[j] = acc[r][j] * aSv[j]; pd[j] = acc[r][j] * aDv[j]; }
            for (int mm = 32; mm >= 1; mm >>= 1) {
#pragma unroll
                for (int j = 0; j < PL; ++j) {
                    ps[j] += __shfl_xor(ps[j], mm, 64);
                    pd[j] += __shfl_xor(pd[j], mm, 64);
                }
            }
            if (ALPHA == 2) {
                if (lane == 0) {
#pragma unroll
                    for (int j = 0; j < PL; ++j) {
                        alpS[n * 2 + j] = ps[j]; alpD[n * 2 + j] = pd[j];
                    }
                }
            } else {
                if (lane == 0) { alpS[n] = ps[0]; alpD[n] = pd[0]; }
            }
        }
    }
}

// ---------------------------------------------------------------------------
// FC via MFMA (R21-proven): wave owns 64 cols, B fragments in registers from
// WT[512][64]; per 16-row tile: 2 x-loads + 8 MFMA + coalesced stores.
// ---------------------------------------------------------------------------
__global__ __launch_bounds__(256) void fcmfma_kernel(
        const __half* __restrict__ in,    // [N][64] fp16
        const __half* __restrict__ WT,    // [512][64] fp16 (transposed)
        const float* __restrict__ bias,   // [512]
        float* __restrict__ out,          // [N][512]
        int N, int NT) {
    const int wid  = threadIdx.x >> 6;
    const int lane = threadIdx.x & 63;
    const int cb = blockIdx.y * 256 + wid * 64;
    const int r  = lane & 15;     // A-row / B-col / D-col within tile
    const int kg = lane >> 4;     // k-group

    f16x8 bfrag[4][2];
#pragma unroll
    for (int t = 0; t < 4; ++t)
#pragma unroll
        for (int kf = 0; kf < 2; ++kf)
            bfrag[t][kf] = *(const f16x8*)(WT + (size_t)(cb + t * 16 + r) * 64 + kf * 32 + kg * 8);
    float bs[4];
#pragma unroll
    for (int t = 0; t < 4; ++t) bs[t] = bias[cb + t * 16 + r];

    const int rt0 = blockIdx.x * 5;
#pragma unroll 1
    for (int q = 0; q < 5; ++q) {
        const int rt = rt0 + q;
        if (rt >= NT) break;
        const int n0 = rt * 16;
        f16x8 a0 = *(const f16x8*)(in + (size_t)(n0 + r) * 64 + kg * 8);
        f16x8 a1 = *(const f16x8*)(in + (size_t)(n0 + r) * 64 + 32 + kg * 8);
#pragma unroll
        for (int t = 0; t < 4; ++t) {
            f32x4 acc = {0.0f, 0.0f, 0.0f, 0.0f};
            acc = __builtin_amdgcn_mfma_f32_16x16x32_f16(a0, bfrag[t][0], acc, 0, 0, 0);
            acc = __builtin_amdgcn_mfma_f32_16x16x32_f16(a1, bfrag[t][1], acc, 0, 0, 0);
#pragma unroll
            for (int i = 0; i < 4; ++i) {
                int grow = n0 + kg * 4 + i;
                if (grow < N)
                    out[(size_t)grow * 512 + cb + t * 16 + r] = fmaxf(acc[i] + bs[t], 0.0f);
            }
        }
    }
}

// ---------------------------------------------------------------------------
// Aggregate (PL1 variants, layers 1+3): one wave per dst node, 64-edge
// chunks, two-phase; h gathered as FP16; softmax/accumulate fp32; fp16 out.
// ---------------------------------------------------------------------------
template <int H, int C>
__global__ __launch_bounds__(256) void aggregate_kernel(
        const __half* __restrict__ h,
        const float* __restrict__ alpha_s,
        const float* __restrict__ alpha_d,
        const int* __restrict__ row_ptr,
        const int* __restrict__ csr_src,
        const float* __restrict__ bias,
        __half* __restrict__ out, int N) {
    constexpr int M = H * C;
    __shared__ int   ss[4][64];
    __shared__ float sp[4][128];
    const int wid  = threadIdx.x >> 6;
    const int lane = threadIdx.x & 63;
    const int n = blockIdx.x * 4 + wid;
    if (n >= N) return;

    const int lo = row_ptr[n], hi = row_ptr[n + 1];
    const int myhead = (H == 2) ? (lane / C) : 0;

    float adv[H];
#pragma unroll
    for (int t = 0; t < H; ++t) adv[t] = alpha_d[n * H + t];

    float m[H], den[H], acc = 0.0f;
#pragma unroll
    for (int t = 0; t < H; ++t) { m[t] = -INFINITY; den[t] = 0.0f; }

    for (int e0 = lo; e0 < hi; e0 += 64) {
        const int idx = e0 + lane;
        const bool valid = idx < hi;
        const int src_l = csr_src[valid ? idx : hi - 1];

        // ---- phase A: lane-parallel logits ----
        float lg[H];
        if (H == 2) {
            float2 as = ((const float2*)alpha_s)[src_l];
            lg[0] = as.x + adv[0];
            lg[1] = as.y + adv[1];
        } else {
            lg[0] = alpha_s[src_l] + adv[0];
        }
#pragma unroll
        for (int t = 0; t < H; ++t) {
            float v = lg[t];
            v = v > 0.0f ? v : 0.2f * v;
            lg[t] = valid ? v : -INFINITY;
        }
        float cm[H];
#pragma unroll
        for (int t = 0; t < H; ++t) cm[t] = lg[t];
        for (int mm = 32; mm >= 1; mm >>= 1) {
#pragma unroll
            for (int t = 0; t < H; ++t)
                cm[t] = fmaxf(cm[t], __shfl_xor(cm[t], mm, 64));
        }
        float sc[H];
#pragma unroll
        for (int t = 0; t < H; ++t) {
            float mnew = fmaxf(m[t], cm[t]);
            sc[t] = __expf(m[t] - mnew);
            den[t] *= sc[t];
            m[t] = mnew;
        }
        acc *= (H == 1) ? sc[0] : (myhead == 0 ? sc[0] : sc[1]);

        float p[H], dsum[H];
#pragma unroll
        for (int t = 0; t < H; ++t) { p[t] = __expf(lg[t] - m[t]); dsum[t] = p[t]; }
        for (int mm = 32; mm >= 1; mm >>= 1) {
#pragma unroll
            for (int t = 0; t < H; ++t)
                dsum[t] += __shfl_xor(dsum[t], mm, 64);
        }
#pragma unroll
        for (int t = 0; t < H; ++t) den[t] += dsum[t];

        ss[wid][lane] = src_l;
        if (H == 2) ((float2*)sp[wid])[lane] = make_float2(p[0], p[1]);
        else        sp[wid][lane] = p[0];

        // ---- phase B: per-edge broadcast accumulate, 8-wide batch ----
        int nu = hi - e0; if (nu > 64) nu = 64;
        int u = 0;
#pragma unroll 1
        for (; u + 8 <= nu; u += 8) {
            int su[8];
#pragma unroll
            for (int t = 0; t < 8; ++t)
                su[t] = __builtin_amdgcn_readfirstlane(ss[wid][u + t]);
            float hv[8];
#pragma unroll
            for (int t = 0; t < 8; ++t)
                hv[t] = __half2float(h[(size_t)su[t] * M + lane]);
            if (H == 2) {
                const float2* pb = (const float2*)sp[wid];
#pragma unroll
                for (int t = 0; t < 8; ++t) {
                    float2 q = pb[u + t];
                    acc += (myhead == 0 ? q.x : q.y) * hv[t];
                }
            } else {
#pragma unroll
                for (int t = 0; t < 8; ++t)
                    acc += sp[wid][u + t] * hv[t];
            }
        }
#pragma unroll 1
        for (; u < nu; ++u) {
            int su = __builtin_amdgcn_readfirstlane(ss[wid][u]);
            float hv = __half2float(h[(size_t)su * M + lane]);
            if (H == 2) {
                float2 q = ((const float2*)sp[wid])[u];
                acc += (myhead == 0 ? q.x : q.y) * hv;
            } else {
                acc += sp[wid][u] * hv;
            }
        }
    }

    float dv = (H == 1) ? den[0] : (myhead == 0 ? den[0] : den[1]);
    float v = acc / dv + bias[lane];
    out[(size_t)n * M + lane] = (__half)fmaxf(v, 0.0f);
}

// ---------------------------------------------------------------------------
// Layer-2 aggregate, HEAD-SPLIT: 2 waves per node; h fp16 in, fp16 out.
// ---------------------------------------------------------------------------
__global__ __launch_bounds__(256) void aggregate2_kernel(
        const __half* __restrict__ h,       // [N][128] fp16
        const float* __restrict__ alpha_s,  // [N][2]
        const float* __restrict__ alpha_d,  // [N][2]
        const int* __restrict__ row_ptr,
        const int* __restrict__ csr_src,
        const float* __restrict__ bias,     // [128]
        __half* __restrict__ out, int N) {
    __shared__ int   ss[4][64];
    __shared__ float sp[4][64];
    const int wid  = threadIdx.x >> 6;
    const int lane = threadIdx.x & 63;
    const int gw   = blockIdx.x * 4 + wid;
    const int n    = gw >> 1;
    const int hd   = gw & 1;
    if (n >= N) return;

    const int lo = row_ptr[n], hi = row_ptr[n + 1];
    const float adv = alpha_d[n * 2 + hd];

    float m = -INFINITY, den = 0.0f, acc = 0.0f;

    for (int e0 = lo; e0 < hi; e0 += 64) {
        const int idx = e0 + lane;
        const bool valid = idx < hi;
        const int src_l = csr_src[valid ? idx : hi - 1];

        float lg = alpha_s[src_l * 2 + hd] + adv;
        lg = lg > 0.0f ? lg : 0.2f * lg;
        if (!valid) lg = -INFINITY;

        float cm = lg;
        for (int mm = 32; mm >= 1; mm >>= 1)
            cm = fmaxf(cm, __shfl_xor(cm, mm, 64));

        float mnew = fmaxf(m, cm);
        float sc = __expf(m - mnew);
        den *= sc; acc *= sc; m = mnew;

        float p = __expf(lg - m), ds = p;
        for (int mm = 32; mm >= 1; mm >>= 1)
            ds += __shfl_xor(ds, mm, 64);
        den += ds;

        ss[wid][lane] = src_l;
        sp[wid][lane] = p;

        int nu = hi - e0; if (nu > 64) nu = 64;
        int u = 0;
#pragma unroll 1
        for (; u + 8 <= nu; u += 8) {
            int su[8];
#pragma unroll
            for (int t = 0; t < 8; ++t)
                su[t] = __builtin_amdgcn_readfirstlane(ss[wid][u + t]);
            float hv[8];
#pragma unroll
            for (int t = 0; t < 8; ++t)
                hv[t] = __half2float(h[(size_t)su[t] * 128 + hd * 64 + lane]);
#pragma unroll
            for (int t = 0; t < 8; ++t)
                acc += sp[wid][u + t] * hv[t];
        }
#pragma unroll 1
        for (; u < nu; ++u) {
            int su = __builtin_amdgcn_readfirstlane(ss[wid][u]);
            acc += sp[wid][u] * __half2float(h[(size_t)su * 128 + hd * 64 + lane]);
        }
    }

    float v = acc / den + bias[hd * 64 + lane];
    out[(size_t)n * 128 + hd * 64 + lane] = (__half)fmaxf(v, 0.0f);
}

// ---------------------------------------------------------------------------

extern "C" void kernel_launch(void* const* d_in, const int* in_sizes, int n_in,
                              void* d_out, int out_size, void* d_ws, size_t ws_size,
                              hipStream_t stream) {
    const float* x   = (const float*)d_in[0];
    const int*   ei  = (const int*)  d_in[1];
    const float* w1  = (const float*)d_in[2];
    const float* as1 = (const float*)d_in[3];
    const float* ad1 = (const float*)d_in[4];
    const float* b1  = (const float*)d_in[5];
    const float* w2  = (const float*)d_in[6];
    const float* as2 = (const float*)d_in[7];
    const float* ad2 = (const float*)d_in[8];
    const float* b2  = (const float*)d_in[9];
    const float* w3  = (const float*)d_in[10];
    const float* as3 = (const float*)d_in[11];
    const float* ad3 = (const float*)d_in[12];
    const float* b3  = (const float*)d_in[13];
    const float* fcw = (const float*)d_in[14];
    const float* fcb = (const float*)d_in[15];
    float* out = (float*)d_out;

    const int N = in_sizes[0] / 128;
    const int E = in_sizes[1] / 2;
    const int Etot = E + N;

    // workspace carve-up (256B aligned regions)
    char* p = (char*)d_ws;
    auto alloc = [&](size_t bytes) {
        char* r = p;
        p += (bytes + 255) & ~(size_t)255;
        return r;
    };
    int*    cnt     = (int*)   alloc((size_t)N * 4);
    int*    row_ptr = (int*)   alloc((size_t)(N + 1) * 4);
    int*    rank    = (int*)   alloc((size_t)Etot * 4);
    int*    csr_src = (int*)   alloc((size_t)Etot * 4);
    int*    bsum    = (int*)   alloc((size_t)SCAN_NB * 4);
    int*    bbase   = (int*)   alloc((size_t)SCAN_NB * 4);
    __half* bufA    = (__half*)alloc((size_t)N * 128 * 2);   // fp16 gemm out h
    __half* bufB    = (__half*)alloc((size_t)N * 128 * 2);   // fp16 agg out
    __half* bufC    = (__half*)alloc((size_t)(N + 16) * 64 * 2); // fp16 agg3 out (FC in, +pad)
    __half* wh2     = (__half*)alloc((size_t)8192 * 2);
    __half* wh3     = (__half*)alloc((size_t)8192 * 2);
    __half* fcwT    = (__half*)alloc((size_t)32768 * 2);     // [512][64] transposed
    float*  alpS    = (float*) alloc((size_t)N * 2 * 4);
    float*  alpD    = (float*) alloc((size_t)N * 2 * 4);
    (void)ws_size; (void)n_in; (void)out_size;

    hipMemsetAsync(cnt, 0, (size_t)N * 4, stream);

    // ---- fused: count_rank + gemm1(fp32 in) + cvtw, one launch ----
    const int CNTB  = (Etot / 4 + 255) / 256 + 1;   // unroll-4 coverage (~1613)
    const int GEMMB = 1024;                          // gemm1 blocks
    const int WB    = 192;                           // cvtw blocks (49152/256)
    layer1_fused_kernel<<<CNTB + GEMMB + WB, 256, 0, stream>>>(
        x, w1, bufA, as1, ad1, alpS, alpD, N,
        ei, E, cnt, rank, w2, w3, fcw, wh2, wh3, fcwT,
        CNTB, GEMMB);

    // ---- CSR: parallel scan + scatter ----
    scanA_kernel<<<SCAN_NB, 256, 0, stream>>>(cnt, N, bsum);
    scanB_kernel<<<1, 256, 0, stream>>>(bsum, bbase);
    scanC_kernel<<<SCAN_NB, 256, 0, stream>>>(cnt, N, Etot, bbase, row_ptr);
    const int CB = (Etot / 4 + 255) / 256 + 1;
    scatter_kernel<<<CB, 256, 0, stream>>>(ei, E, N, row_ptr, rank, csr_src);

    int gb  = (N + 3) / 4;        // aggregate (PL1): 4 waves/block, 1 node/wave
    int gb2 = (2 * N + 3) / 4;    // aggregate2: 2 waves/node
    const int GB16 = 2048;        // fp16 gemm grids (layers 2,3)

    // ---- layer 1 aggregate ----
    aggregate_kernel<2, 32><<<gb, 256, 0, stream>>>(bufA, alpS, alpD, row_ptr, csr_src, b1, bufB, N);

    // ---- layer 2: 64 -> H2 x C64, concat (head-split aggregate) ----
    gemm16_kernel<64, 128, 8, 2><<<dim3(GB16, 1), 256, 0, stream>>>(
        bufB, wh2, bufA, as2, ad2, alpS, alpD, N, 128);
    aggregate2_kernel<<<gb2, 256, 0, stream>>>(bufA, alpS, alpD, row_ptr, csr_src, b2, bufB, N);

    // ---- layer 3: 128 -> H1 x C64, mean; output fp16 for FC ----
    gemm16_kernel<128, 64, 8, 3><<<dim3(GB16, 1), 256, 0, stream>>>(
        bufB, wh3, bufA, as3, ad3, alpS, alpD, N, 64);
    aggregate_kernel<1, 64><<<gb, 256, 0, stream>>>(bufA, alpS, alpD, row_ptr, csr_src, b3, bufC, N);

    // ---- FC: 64 -> 512 + relu via MFMA, B-fragments in registers ----
    const int NT = (N + 15) / 16;               // 16-row tiles (3125 exact)
    const int GX = (NT + 4) / 5;                // 5 tiles/block (625)
    fcmfma_kernel<<<dim3(GX, 2), 256, 0, stream>>>(
        bufC, fcwT, fcb, out, N, NT);
}

// Round 17
// 587.767 us; speedup vs baseline: 1.0253x; 1.0253x over previous
//
#include <hip/hip_runtime.h>
#include <hip/hip_fp16.h>
#include <math.h>

// ---------------------------------------------------------------------------
// GAT pipeline: 3x (GEMM16+alpha fused -> CSR segment-softmax aggregate) + FC
// R24: revert R23's three-role fusion (fp32-x gemm1 without ping-pong was
//      ~140us latency-bound, fused 147us, total +18). Back to R22 EXACTLY
//      (584.7us proven) with ONE change: the count role's grid-stride
//      unroll-1 loop (which serialized each thread's atomics on the returned
//      value) becomes a batched unroll-7 strided loop -- 7 independent
//      atomicAdds in flight per thread (R21's atomic MLP) at R22's grid.
// ---------------------------------------------------------------------------

typedef _Float16 h2_t __attribute__((ext_vector_type(2)));
typedef _Float16 f16x8 __attribute__((ext_vector_type(8)));
typedef float f32x4 __attribute__((ext_vector_type(4)));

__device__ __forceinline__ h2_t as_h2(unsigned int u) {
    union { unsigned int u; h2_t h; } x; x.u = u; return x.h;
}

__device__ __forceinline__ float fdot2(h2_t a, h2_t b, float c) {
#if __has_builtin(__builtin_amdgcn_fdot2)
    return __builtin_amdgcn_fdot2(a, b, c, false);
#else
    return c + (float)a[0] * (float)b[0] + (float)a[1] * (float)b[1];
#endif
}

// ---------------------------------------------------------------------------
// cvt: blocks [0,XB) convert x fp32->fp16; blocks [XB,XB+WB) convert the 3
// layer weights + transposed fc weight. Pure streaming.
// ---------------------------------------------------------------------------
__global__ void cvt_kernel(
        const float* __restrict__ x, __half* __restrict__ xh, int n4,
        const float* __restrict__ w1, const float* __restrict__ w2,
        const float* __restrict__ w3, const float* __restrict__ fcw,
        __half* __restrict__ o1, __half* __restrict__ o2,
        __half* __restrict__ o3, __half* __restrict__ o4T,
        int XB) {
    const int b = blockIdx.x;
    if (b < XB) {
        int i = b * 256 + threadIdx.x;
        if (i < n4) {
            float4 v = ((const float4*)x)[i];
            __half2 a, c;
            a.x = (__half)v.x; a.y = (__half)v.y;
            c.x = (__half)v.z; c.y = (__half)v.w;
            ((__half2*)xh)[2 * i]     = a;
            ((__half2*)xh)[2 * i + 1] = c;
        }
    } else {
        int i = (b - XB) * 256 + threadIdx.x;
        if (i < 8192)       o1[i]         = (__half)w1[i];
        else if (i < 16384) o2[i - 8192]  = (__half)w2[i - 8192];
        else if (i < 24576) o3[i - 16384] = (__half)w3[i - 16384];
        else if (i < 57344) {
            int j = i - 24576;              // fcw is [64][512] row-major
            int k = j >> 9, c = j & 511;
            o4T[c * 64 + k] = (__half)fcw[j];   // -> [512][64] transposed
        }
    }
}

// ---------------------------------------------------------------------------
// Parallel scan, 3 phases. NB=256 blocks, chunk = ceil(N/NB) <= 256.
// ---------------------------------------------------------------------------
#define SCAN_NB 256

__global__ __launch_bounds__(256) void scanA_kernel(const int* __restrict__ cnt,
                                                    int N, int* __restrict__ bsum) {
    __shared__ int red[256];
    const int chunk = (N + SCAN_NB - 1) / SCAN_NB;
    const int lo = blockIdx.x * chunk;
    const int len = min(N - lo, chunk);
    int s = 0;
    for (int i = threadIdx.x; i < len; i += 256) s += cnt[lo + i];
    red[threadIdx.x] = s;
    __syncthreads();
    for (int off = 128; off >= 1; off >>= 1) {
        if (threadIdx.x < off) red[threadIdx.x] += red[threadIdx.x + off];
        __syncthreads();
    }
    if (threadIdx.x == 0) bsum[blockIdx.x] = red[0];
}

__global__ __launch_bounds__(256) void scanB_kernel(int* __restrict__ bsum,
                                                    int* __restrict__ bbase) {
    __shared__ int s[256];
    int v = bsum[threadIdx.x];
    s[threadIdx.x] = v;
    __syncthreads();
    for (int off = 1; off < 256; off <<= 1) {
        int t = (threadIdx.x >= off) ? s[threadIdx.x - off] : 0;
        __syncthreads();
        s[threadIdx.x] += t;
        __syncthreads();
    }
    bbase[threadIdx.x] = s[threadIdx.x] - v;   // exclusive
}

__global__ __launch_bounds__(256) void scanC_kernel(const int* __restrict__ cnt,
                                                    int N, int Etot,
                                                    const int* __restrict__ bbase,
                                                    int* __restrict__ row_ptr) {
    __shared__ int s[256];
    const int chunk = (N + SCAN_NB - 1) / SCAN_NB;
    const int lo = blockIdx.x * chunk;
    const int len = min(N - lo, chunk);
    const int t = threadIdx.x;
    int v = (t < len) ? cnt[lo + t] : 0;
    s[t] = v;
    __syncthreads();
    for (int off = 1; off < 256; off <<= 1) {
        int u = (t >= off) ? s[t - off] : 0;
        __syncthreads();
        s[t] += u;
        __syncthreads();
    }
    if (t < len) row_ptr[lo + t] = bbase[blockIdx.x] + s[t] - v;
    if (blockIdx.x == 0 && t == 0) row_ptr[N] = Etot;
}

// pass 3: pos = row_ptr[dst] + rank[e]; atomic-free scattered store.
__global__ void scatter_kernel(const int* __restrict__ ei, int E, int N,
                               const int* __restrict__ row_ptr,
                               const int* __restrict__ rank,
                               int* __restrict__ csr_src) {
    const int Etot = E + N;
    const int T = gridDim.x * blockDim.x;
    int e = blockIdx.x * blockDim.x + threadIdx.x;
#pragma unroll 4
    for (int u = 0; u < 4; ++u, e += T) {
        if (e < Etot) {
            int src, dst;
            if (e < E) { src = ei[e]; dst = ei[E + e]; }
            else       { src = e - E; dst = e - E; }
            csr_src[row_ptr[dst] + rank[e]] = src;
        }
    }
}

// ---------------------------------------------------------------------------
// Layer GEMM, fp16 in/W, fp32 acc via fdot2, fp16 out, fused alpha (R18).
// COUNT variant (layer 1): blocks [GGEMM, gridDim) run count_rank with a
// batched unroll-7 strided loop (7 independent atomics in flight/thread)
// concurrently with the gemm blocks.
// ALPHA: 1=(H2,C32: segmented 32-lane)  2=(H2,C64,PL2)  3=(H1,C64)
// ---------------------------------------------------------------------------
template <int K, int CHUNK, int RB, int ALPHA, bool COUNT>
__global__ __launch_bounds__(256) void gemm16_kernel(
        const __half* __restrict__ in,
        const __half* __restrict__ Wh,
        __half* __restrict__ out,
        const float* __restrict__ a_src,
        const float* __restrict__ a_dst,
        float* __restrict__ alpS,
        float* __restrict__ alpD,
        int N, int M,
        const int* __restrict__ ei, int E,
        int* __restrict__ cnt, int* __restrict__ rank,
        int GGEMM) {
    constexpr int PL = CHUNK / 64;
    constexpr int K4 = K / 4;
    __shared__ uint2 wlds[K4 * CHUNK];   // 16 KB

    if (COUNT && blockIdx.x >= GGEMM) {
        // ---- count_rank: 7 batched atomics/thread (restored MLP) ----
        const int Etot = E + N;
        const int T = (gridDim.x - GGEMM) * 256;
        int e = (blockIdx.x - GGEMM) * 256 + threadIdx.x;
#pragma unroll 7
        for (int u = 0; u < 7; ++u, e += T) {
            if (e < Etot) {
                int dst = (e < E) ? ei[E + e] : (e - E);   // self-loops appended
                rank[e] = atomicAdd(&cnt[dst], 1);
            }
        }
        return;
    }
    const int GSTRIDE = COUNT ? GGEMM : gridDim.x;

    const unsigned short* wsrc = (const unsigned short*)Wh;
    for (int idx = threadIdx.x; idx < K4 * CHUNK; idx += 256) {
        int k4 = idx / CHUNK, c = idx % CHUNK;
        const unsigned short* wp = wsrc + (size_t)(4 * k4) * M + c;
        uint2 v;
        v.x = (unsigned int)wp[0]     | ((unsigned int)wp[M] << 16);
        v.y = (unsigned int)wp[2 * M] | ((unsigned int)wp[3 * M] << 16);
        wlds[idx] = v;
    }
    __syncthreads();

    const int wid  = threadIdx.x >> 6;
    const int lane = threadIdx.x & 63;

    float aSv[PL], aDv[PL];
#pragma unroll
    for (int j = 0; j < PL; ++j) {
        aSv[j] = a_src[lane + 64 * j];
        aDv[j] = a_dst[lane + 64 * j];
    }

    const int groups = (N + RB - 1) / RB;
    for (int g = blockIdx.x * 4 + wid; g < groups; g += GSTRIDE * 4) {
        const int n0 = g * RB;
        const bool full = (n0 + RB <= N);

        float acc[RB][PL];
#pragma unroll
        for (int r = 0; r < RB; ++r)
#pragma unroll
            for (int j = 0; j < PL; ++j) acc[r][j] = 0.0f;

        const uint2* xp = (const uint2*)(in + (size_t)n0 * K);

        if (full) {
            uint2 xv[RB], xn[RB];
#pragma unroll
            for (int r = 0; r < RB; ++r) xv[r] = xp[r * K4];
#pragma unroll 2
            for (int k4 = 0; k4 < K4; ++k4) {
                if (k4 + 1 < K4) {
#pragma unroll
                    for (int r = 0; r < RB; ++r)
                        xn[r] = xp[r * K4 + k4 + 1];
                }
#pragma unroll
                for (int j = 0; j < PL; ++j) {
                    uint2 wv = wlds[k4 * CHUNK + lane + 64 * j];
#pragma unroll
                    for (int r = 0; r < RB; ++r) {
                        acc[r][j] = fdot2(as_h2(xv[r].x), as_h2(wv.x), acc[r][j]);
                        acc[r][j] = fdot2(as_h2(xv[r].y), as_h2(wv.y), acc[r][j]);
                    }
                }
                if (k4 + 1 < K4) {
#pragma unroll
                    for (int r = 0; r < RB; ++r) xv[r] = xn[r];
                }
            }
        } else {
#pragma unroll 1
            for (int k4 = 0; k4 < K4; ++k4) {
#pragma unroll 1
                for (int r = 0; r < RB; ++r) {
                    if (n0 + r >= N) break;
                    uint2 xr = xp[(size_t)r * K4 + k4];
#pragma unroll
                    for (int j = 0; j < PL; ++j) {
                        uint2 wv = wlds[k4 * CHUNK + lane + 64 * j];
                        acc[r][j] = fdot2(as_h2(xr.x), as_h2(wv.x), acc[r][j]);
                        acc[r][j] = fdot2(as_h2(xr.y), as_h2(wv.y), acc[r][j]);
                    }
                }
            }
        }

#pragma unroll
        for (int r = 0; r < RB; ++r) {
            if (!full && n0 + r >= N) break;
            const int n = n0 + r;
#pragma unroll
            for (int j = 0; j < PL; ++j)
                out[(size_t)n * M + lane + 64 * j] = (__half)acc[r][j];

            float ps[PL], pd[PL];
#pragma unroll
            for (int j = 0; j < PL; ++j) { ps[j] = acc[r][j] * aSv[j]; pd[j] = acc[r][j] * aDv[j]; }
            const int m0 = (ALPHA == 1) ? 16 : 32;
            for (int mm = m0; mm >= 1; mm >>= 1) {
#pragma unroll
                for (int j = 0; j < PL; ++j) {
                    ps[j] += __shfl_xor(ps[j], mm, 64);
                    pd[j] += __shfl_xor(pd[j], mm, 64);
                }
            }
            if (ALPHA == 1) {
                if ((lane & 31) == 0) {
                    int idx = n * 2 + (lane >> 5);
                    alpS[idx] = ps[0]; alpD[idx] = pd[0];
                }
            } else if (ALPHA == 2) {
                if (lane == 0) {
#pragma unroll
                    for (int j = 0; j < PL; ++j) {
                        alpS[n * 2 + j] = ps[j]; alpD[n * 2 + j] = pd[j];
                    }
                }
            } else {
                if (lane == 0) { alpS[n] = ps[0]; alpD[n] = pd[0]; }
            }
        }
    }
}

// ---------------------------------------------------------------------------
// FC via MFMA (R21-proven): wave owns 64 cols, B fragments in registers from
// WT[512][64]; per 16-row tile: 2 x-loads + 8 MFMA + coalesced stores.
// ---------------------------------------------------------------------------
__global__ __launch_bounds__(256) void fcmfma_kernel(
        const __half* __restrict__ in,    // [N][64] fp16
        const __half* __restrict__ WT,    // [512][64] fp16 (transposed)
        const float* __restrict__ bias,   // [512]
        float* __restrict__ out,          // [N][512]
        int N, int NT) {
    const int wid  = threadIdx.x >> 6;
    const int lane = threadIdx.x & 63;
    const int cb = blockIdx.y * 256 + wid * 64;
    const int r  = lane & 15;     // A-row / B-col / D-col within tile
    const int kg = lane >> 4;     // k-group

    f16x8 bfrag[4][2];
#pragma unroll
    for (int t = 0; t < 4; ++t)
#pragma unroll
        for (int kf = 0; kf < 2; ++kf)
            bfrag[t][kf] = *(const f16x8*)(WT + (size_t)(cb + t * 16 + r) * 64 + kf * 32 + kg * 8);
    float bs[4];
#pragma unroll
    for (int t = 0; t < 4; ++t) bs[t] = bias[cb + t * 16 + r];

    const int rt0 = blockIdx.x * 5;
#pragma unroll 1
    for (int q = 0; q < 5; ++q) {
        const int rt = rt0 + q;
        if (rt >= NT) break;
        const int n0 = rt * 16;
        f16x8 a0 = *(const f16x8*)(in + (size_t)(n0 + r) * 64 + kg * 8);
        f16x8 a1 = *(const f16x8*)(in + (size_t)(n0 + r) * 64 + 32 + kg * 8);
#pragma unroll
        for (int t = 0; t < 4; ++t) {
            f32x4 acc = {0.0f, 0.0f, 0.0f, 0.0f};
            acc = __builtin_amdgcn_mfma_f32_16x16x32_f16(a0, bfrag[t][0], acc, 0, 0, 0);
            acc = __builtin_amdgcn_mfma_f32_16x16x32_f16(a1, bfrag[t][1], acc, 0, 0, 0);
#pragma unroll
            for (int i = 0; i < 4; ++i) {
                int grow = n0 + kg * 4 + i;
                if (grow < N)
                    out[(size_t)grow * 512 + cb + t * 16 + r] = fmaxf(acc[i] + bs[t], 0.0f);
            }
        }
    }
}

// ---------------------------------------------------------------------------
// Aggregate (PL1 variants, layers 1+3): one wave per dst node, 64-edge
// chunks, two-phase; h gathered as FP16; softmax/accumulate fp32; fp16 out.
// ---------------------------------------------------------------------------
template <int H, int C>
__global__ __launch_bounds__(256) void aggregate_kernel(
        const __half* __restrict__ h,
        const float* __restrict__ alpha_s,
        const float* __restrict__ alpha_d,
        const int* __restrict__ row_ptr,
        const int* __restrict__ csr_src,
        const float* __restrict__ bias,
        __half* __restrict__ out, int N) {
    constexpr int M = H * C;
    __shared__ int   ss[4][64];
    __shared__ float sp[4][128];
    const int wid  = threadIdx.x >> 6;
    const int lane = threadIdx.x & 63;
    const int n = blockIdx.x * 4 + wid;
    if (n >= N) return;

    const int lo = row_ptr[n], hi = row_ptr[n + 1];
    const int myhead = (H == 2) ? (lane / C) : 0;

    float adv[H];
#pragma unroll
    for (int t = 0; t < H; ++t) adv[t] = alpha_d[n * H + t];

    float m[H], den[H], acc = 0.0f;
#pragma unroll
    for (int t = 0; t < H; ++t) { m[t] = -INFINITY; den[t] = 0.0f; }

    for (int e0 = lo; e0 < hi; e0 += 64) {
        const int idx = e0 + lane;
        const bool valid = idx < hi;
        const int src_l = csr_src[valid ? idx : hi - 1];

        // ---- phase A: lane-parallel logits ----
        float lg[H];
        if (H == 2) {
            float2 as = ((const float2*)alpha_s)[src_l];
            lg[0] = as.x + adv[0];
            lg[1] = as.y + adv[1];
        } else {
            lg[0] = alpha_s[src_l] + adv[0];
        }
#pragma unroll
        for (int t = 0; t < H; ++t) {
            float v = lg[t];
            v = v > 0.0f ? v : 0.2f * v;
            lg[t] = valid ? v : -INFINITY;
        }
        float cm[H];
#pragma unroll
        for (int t = 0; t < H; ++t) cm[t] = lg[t];
        for (int mm = 32; mm >= 1; mm >>= 1) {
#pragma unroll
            for (int t = 0; t < H; ++t)
                cm[t] = fmaxf(cm[t], __shfl_xor(cm[t], mm, 64));
        }
        float sc[H];
#pragma unroll
        for (int t = 0; t < H; ++t) {
            float mnew = fmaxf(m[t], cm[t]);
            sc[t] = __expf(m[t] - mnew);
            den[t] *= sc[t];
            m[t] = mnew;
        }
        acc *= (H == 1) ? sc[0] : (myhead == 0 ? sc[0] : sc[1]);

        float p[H], dsum[H];
#pragma unroll
        for (int t = 0; t < H; ++t) { p[t] = __expf(lg[t] - m[t]); dsum[t] = p[t]; }
        for (int mm = 32; mm >= 1; mm >>= 1) {
#pragma unroll
            for (int t = 0; t < H; ++t)
                dsum[t] += __shfl_xor(dsum[t], mm, 64);
        }
#pragma unroll
        for (int t = 0; t < H; ++t) den[t] += dsum[t];

        ss[wid][lane] = src_l;
        if (H == 2) ((float2*)sp[wid])[lane] = make_float2(p[0], p[1]);
        else        sp[wid][lane] = p[0];

        // ---- phase B: per-edge broadcast accumulate, 8-wide batch ----
        int nu = hi - e0; if (nu > 64) nu = 64;
        int u = 0;
#pragma unroll 1
        for (; u + 8 <= nu; u += 8) {
            int su[8];
#pragma unroll
            for (int t = 0; t < 8; ++t)
                su[t] = __builtin_amdgcn_readfirstlane(ss[wid][u + t]);
            float hv[8];
#pragma unroll
            for (int t = 0; t < 8; ++t)
                hv[t] = __half2float(h[(size_t)su[t] * M + lane]);
            if (H == 2) {
                const float2* pb = (const float2*)sp[wid];
#pragma unroll
                for (int t = 0; t < 8; ++t) {
                    float2 q = pb[u + t];
                    acc += (myhead == 0 ? q.x : q.y) * hv[t];
                }
            } else {
#pragma unroll
                for (int t = 0; t < 8; ++t)
                    acc += sp[wid][u + t] * hv[t];
            }
        }
#pragma unroll 1
        for (; u < nu; ++u) {
            int su = __builtin_amdgcn_readfirstlane(ss[wid][u]);
            float hv = __half2float(h[(size_t)su * M + lane]);
            if (H == 2) {
                float2 q = ((const float2*)sp[wid])[u];
                acc += (myhead == 0 ? q.x : q.y) * hv;
            } else {
                acc += sp[wid][u] * hv;
            }
        }
    }

    float dv = (H == 1) ? den[0] : (myhead == 0 ? den[0] : den[1]);
    float v = acc / dv + bias[lane];
    out[(size_t)n * M + lane] = (__half)fmaxf(v, 0.0f);
}

// ---------------------------------------------------------------------------
// Layer-2 aggregate, HEAD-SPLIT: 2 waves per node; h fp16 in, fp16 out.
// ---------------------------------------------------------------------------
__global__ __launch_bounds__(256) void aggregate2_kernel(
        const __half* __restrict__ h,       // [N][128] fp16
        const float* __restrict__ alpha_s,  // [N][2]
        const float* __restrict__ alpha_d,  // [N][2]
        const int* __restrict__ row_ptr,
        const int* __restrict__ csr_src,
        const float* __restrict__ bias,     // [128]
        __half* __restrict__ out, int N) {
    __shared__ int   ss[4][64];
    __shared__ float sp[4][64];
    const int wid  = threadIdx.x >> 6;
    const int lane = threadIdx.x & 63;
    const int gw   = blockIdx.x * 4 + wid;
    const int n    = gw >> 1;
    const int hd   = gw & 1;
    if (n >= N) return;

    const int lo = row_ptr[n], hi = row_ptr[n + 1];
    const float adv = alpha_d[n * 2 + hd];

    float m = -INFINITY, den = 0.0f, acc = 0.0f;

    for (int e0 = lo; e0 < hi; e0 += 64) {
        const int idx = e0 + lane;
        const bool valid = idx < hi;
        const int src_l = csr_src[valid ? idx : hi - 1];

        float lg = alpha_s[src_l * 2 + hd] + adv;
        lg = lg > 0.0f ? lg : 0.2f * lg;
        if (!valid) lg = -INFINITY;

        float cm = lg;
        for (int mm = 32; mm >= 1; mm >>= 1)
            cm = fmaxf(cm, __shfl_xor(cm, mm, 64));

        float mnew = fmaxf(m, cm);
        float sc = __expf(m - mnew);
        den *= sc; acc *= sc; m = mnew;

        float p = __expf(lg - m), ds = p;
        for (int mm = 32; mm >= 1; mm >>= 1)
            ds += __shfl_xor(ds, mm, 64);
        den += ds;

        ss[wid][lane] = src_l;
        sp[wid][lane] = p;

        int nu = hi - e0; if (nu > 64) nu = 64;
        int u = 0;
#pragma unroll 1
        for (; u + 8 <= nu; u += 8) {
            int su[8];
#pragma unroll
            for (int t = 0; t < 8; ++t)
                su[t] = __builtin_amdgcn_readfirstlane(ss[wid][u + t]);
            float hv[8];
#pragma unroll
            for (int t = 0; t < 8; ++t)
                hv[t] = __half2float(h[(size_t)su[t] * 128 + hd * 64 + lane]);
#pragma unroll
            for (int t = 0; t < 8; ++t)
                acc += sp[wid][u + t] * hv[t];
        }
#pragma unroll 1
        for (; u < nu; ++u) {
            int su = __builtin_amdgcn_readfirstlane(ss[wid][u]);
            acc += sp[wid][u] * __half2float(h[(size_t)su * 128 + hd * 64 + lane]);
        }
    }

    float v = acc / den + bias[hd * 64 + lane];
    out[(size_t)n * 128 + hd * 64 + lane] = (__half)fmaxf(v, 0.0f);
}

// ---------------------------------------------------------------------------

extern "C" void kernel_launch(void* const* d_in, const int* in_sizes, int n_in,
                              void* d_out, int out_size, void* d_ws, size_t ws_size,
                              hipStream_t stream) {
    const float* x   = (const float*)d_in[0];
    const int*   ei  = (const int*)  d_in[1];
    const float* w1  = (const float*)d_in[2];
    const float* as1 = (const float*)d_in[3];
    const float* ad1 = (const float*)d_in[4];
    const float* b1  = (const float*)d_in[5];
    const float* w2  = (const float*)d_in[6];
    const float* as2 = (const float*)d_in[7];
    const float* ad2 = (const float*)d_in[8];
    const float* b2  = (const float*)d_in[9];
    const float* w3  = (const float*)d_in[10];
    const float* as3 = (const float*)d_in[11];
    const float* ad3 = (const float*)d_in[12];
    const float* b3  = (const float*)d_in[13];
    const float* fcw = (const float*)d_in[14];
    const float* fcb = (const float*)d_in[15];
    float* out = (float*)d_out;

    const int N = in_sizes[0] / 128;
    const int E = in_sizes[1] / 2;
    const int Etot = E + N;

    // workspace carve-up (256B aligned regions)
    char* p = (char*)d_ws;
    auto alloc = [&](size_t bytes) {
        char* r = p;
        p += (bytes + 255) & ~(size_t)255;
        return r;
    };
    int*    cnt     = (int*)   alloc((size_t)N * 4);
    int*    row_ptr = (int*)   alloc((size_t)(N + 1) * 4);
    int*    rank    = (int*)   alloc((size_t)Etot * 4);
    int*    csr_src = (int*)   alloc((size_t)Etot * 4);
    int*    bsum    = (int*)   alloc((size_t)SCAN_NB * 4);
    int*    bbase   = (int*)   alloc((size_t)SCAN_NB * 4);
    __half* x16     = (__half*)alloc((size_t)N * 128 * 2);   // fp16 input x
    __half* bufA    = (__half*)alloc((size_t)N * 128 * 2);   // fp16 gemm out h
    __half* bufB    = (__half*)alloc((size_t)N * 128 * 2);   // fp16 agg out
    __half* bufC    = (__half*)alloc((size_t)(N + 16) * 64 * 2); // fp16 agg3 out (FC in, +pad)
    __half* wh1     = (__half*)alloc((size_t)8192 * 2);
    __half* wh2     = (__half*)alloc((size_t)8192 * 2);
    __half* wh3     = (__half*)alloc((size_t)8192 * 2);
    __half* fcwT    = (__half*)alloc((size_t)32768 * 2);     // [512][64] transposed
    float*  alpS    = (float*) alloc((size_t)N * 2 * 4);
    float*  alpD    = (float*) alloc((size_t)N * 2 * 4);
    (void)ws_size; (void)n_in; (void)out_size;

    // ---- cvt: x fp32->fp16 + weights (streaming) ----
    hipMemsetAsync(cnt, 0, (size_t)N * 4, stream);
    const int n4 = N * 32;                      // float4 units in x
    const int XB = (n4 + 255) / 256;            // cvtx blocks
    const int WB = 224;                         // cvtw blocks
    cvt_kernel<<<XB + WB, 256, 0, stream>>>(
        x, x16, n4, w1, w2, w3, fcw, wh1, wh2, wh3, fcwT, XB);

    int gb  = (N + 3) / 4;        // aggregate (PL1): 4 waves/block, 1 node/wave
    int gb2 = (2 * N + 3) / 4;    // aggregate2: 2 waves/node
    const int GB16 = 2048;        // fp16 gemm grids (layers 2,3)
    const int GG1  = 1024;        // layer-1 gemm blocks (fused with count)
    const int GC1  = 1024;        // count blocks co-resident with gemm1

    // ---- layer 1 GEMM fused with count_rank (batched atomics + fdot2) ----
    gemm16_kernel<128, 64, 8, 1, true><<<dim3(GG1 + GC1, 1), 256, 0, stream>>>(
        x16, wh1, bufA, as1, ad1, alpS, alpD, N, 64, ei, E, cnt, rank, GG1);

    // ---- CSR: parallel scan + scatter ----
    scanA_kernel<<<SCAN_NB, 256, 0, stream>>>(cnt, N, bsum);
    scanB_kernel<<<1, 256, 0, stream>>>(bsum, bbase);
    scanC_kernel<<<SCAN_NB, 256, 0, stream>>>(cnt, N, Etot, bbase, row_ptr);
    const int CB = (Etot / 4 + 255) / 256 + 1;
    scatter_kernel<<<CB, 256, 0, stream>>>(ei, E, N, row_ptr, rank, csr_src);

    // ---- layer 1 aggregate ----
    aggregate_kernel<2, 32><<<gb, 256, 0, stream>>>(bufA, alpS, alpD, row_ptr, csr_src, b1, bufB, N);

    // ---- layer 2: 64 -> H2 x C64, concat (head-split aggregate) ----
    gemm16_kernel<64, 128, 8, 2, false><<<dim3(GB16, 1), 256, 0, stream>>>(
        bufB, wh2, bufA, as2, ad2, alpS, alpD, N, 128, nullptr, 0, nullptr, nullptr, GB16);
    aggregate2_kernel<<<gb2, 256, 0, stream>>>(bufA, alpS, alpD, row_ptr, csr_src, b2, bufB, N);

    // ---- layer 3: 128 -> H1 x C64, mean; output fp16 for FC ----
    gemm16_kernel<128, 64, 8, 3, false><<<dim3(GB16, 1), 256, 0, stream>>>(
        bufB, wh3, bufA, as3, ad3, alpS, alpD, N, 64, nullptr, 0, nullptr, nullptr, GB16);
    aggregate_kernel<1, 64><<<gb, 256, 0, stream>>>(bufA, alpS, alpD, row_ptr, csr_src, b3, bufC, N);

    // ---- FC: 64 -> 512 + relu via MFMA, B-fragments in registers ----
    const int NT = (N + 15) / 16;               // 16-row tiles (3125 exact)
    const int GX = (NT + 4) / 5;                // 5 tiles/block (625)
    fcmfma_kernel<<<dim3(GX, 2), 256, 0, stream>>>(
        bufC, fcwT, fcb, out, N, NT);
}

// Round 18
// 517.595 us; speedup vs baseline: 1.1643x; 1.1356x over previous
//
#include <hip/hip_runtime.h>
#include <hip/hip_fp16.h>
#include <math.h>

// ---------------------------------------------------------------------------
// GAT pipeline: 3x (GEMM+alpha fused -> CSR segment-softmax aggregate) + FC
// R25: gemm2/gemm3 moved to MFMA (R21's proven fcmfma structure: register-
//      resident B from transposed fp16 W, 16-row tiles, no LDS/barriers).
//      Fused alpha computed from the MFMA accumulator: lane partial
//      sum_t acc[t][i]*a[col], reduced over the 16-lane r-group (shfl_xor
//      1,2,4,8), r==0 writes rows kg*4+i. gemm2: wave owns one head's 64
//      cols -> per-head alpha directly. Atomic wall closed (R22/23/24:
//      count is coherence-point-rate-bound, ~87us, hidden under gemm1).
//      All else = R24 (587.8us ~ R22's 584.7 proven).
// ---------------------------------------------------------------------------

typedef _Float16 h2_t __attribute__((ext_vector_type(2)));
typedef _Float16 f16x8 __attribute__((ext_vector_type(8)));
typedef float f32x4 __attribute__((ext_vector_type(4)));

__device__ __forceinline__ h2_t as_h2(unsigned int u) {
    union { unsigned int u; h2_t h; } x; x.u = u; return x.h;
}

__device__ __forceinline__ float fdot2(h2_t a, h2_t b, float c) {
#if __has_builtin(__builtin_amdgcn_fdot2)
    return __builtin_amdgcn_fdot2(a, b, c, false);
#else
    return c + (float)a[0] * (float)b[0] + (float)a[1] * (float)b[1];
#endif
}

// ---------------------------------------------------------------------------
// cvt: blocks [0,XB) convert x fp32->fp16; blocks [XB,XB+WB) convert w1
// (linear, for fused gemm1 LDS path) + w2/w3/fcw TRANSPOSED (for MFMA
// register-B kernels: WT[col][k]).
// ---------------------------------------------------------------------------
__global__ void cvt_kernel(
        const float* __restrict__ x, __half* __restrict__ xh, int n4,
        const float* __restrict__ w1, const float* __restrict__ w2,
        const float* __restrict__ w3, const float* __restrict__ fcw,
        __half* __restrict__ o1, __half* __restrict__ o2T,
        __half* __restrict__ o3T, __half* __restrict__ o4T,
        int XB) {
    const int b = blockIdx.x;
    if (b < XB) {
        int i = b * 256 + threadIdx.x;
        if (i < n4) {
            float4 v = ((const float4*)x)[i];
            __half2 a, c;
            a.x = (__half)v.x; a.y = (__half)v.y;
            c.x = (__half)v.z; c.y = (__half)v.w;
            ((__half2*)xh)[2 * i]     = a;
            ((__half2*)xh)[2 * i + 1] = c;
        }
    } else {
        int i = (b - XB) * 256 + threadIdx.x;
        if (i < 8192) {
            o1[i] = (__half)w1[i];                  // linear [128][64]
        } else if (i < 16384) {
            int j = i - 8192;                       // w2 [64][128]
            int k = j >> 7, c = j & 127;
            o2T[c * 64 + k] = (__half)w2[j];        // -> [128][64]
        } else if (i < 24576) {
            int j = i - 16384;                      // w3 [128][64]
            int k = j >> 6, c = j & 63;
            o3T[c * 128 + k] = (__half)w3[j];       // -> [64][128]
        } else if (i < 57344) {
            int j = i - 24576;                      // fcw [64][512]
            int k = j >> 9, c = j & 511;
            o4T[c * 64 + k] = (__half)fcw[j];       // -> [512][64]
        }
    }
}

// ---------------------------------------------------------------------------
// Parallel scan, 3 phases. NB=256 blocks, chunk = ceil(N/NB) <= 256.
// ---------------------------------------------------------------------------
#define SCAN_NB 256

__global__ __launch_bounds__(256) void scanA_kernel(const int* __restrict__ cnt,
                                                    int N, int* __restrict__ bsum) {
    __shared__ int red[256];
    const int chunk = (N + SCAN_NB - 1) / SCAN_NB;
    const int lo = blockIdx.x * chunk;
    const int len = min(N - lo, chunk);
    int s = 0;
    for (int i = threadIdx.x; i < len; i += 256) s += cnt[lo + i];
    red[threadIdx.x] = s;
    __syncthreads();
    for (int off = 128; off >= 1; off >>= 1) {
        if (threadIdx.x < off) red[threadIdx.x] += red[threadIdx.x + off];
        __syncthreads();
    }
    if (threadIdx.x == 0) bsum[blockIdx.x] = red[0];
}

__global__ __launch_bounds__(256) void scanB_kernel(int* __restrict__ bsum,
                                                    int* __restrict__ bbase) {
    __shared__ int s[256];
    int v = bsum[threadIdx.x];
    s[threadIdx.x] = v;
    __syncthreads();
    for (int off = 1; off < 256; off <<= 1) {
        int t = (threadIdx.x >= off) ? s[threadIdx.x - off] : 0;
        __syncthreads();
        s[threadIdx.x] += t;
        __syncthreads();
    }
    bbase[threadIdx.x] = s[threadIdx.x] - v;   // exclusive
}

__global__ __launch_bounds__(256) void scanC_kernel(const int* __restrict__ cnt,
                                                    int N, int Etot,
                                                    const int* __restrict__ bbase,
                                                    int* __restrict__ row_ptr) {
    __shared__ int s[256];
    const int chunk = (N + SCAN_NB - 1) / SCAN_NB;
    const int lo = blockIdx.x * chunk;
    const int len = min(N - lo, chunk);
    const int t = threadIdx.x;
    int v = (t < len) ? cnt[lo + t] : 0;
    s[t] = v;
    __syncthreads();
    for (int off = 1; off < 256; off <<= 1) {
        int u = (t >= off) ? s[t - off] : 0;
        __syncthreads();
        s[t] += u;
        __syncthreads();
    }
    if (t < len) row_ptr[lo + t] = bbase[blockIdx.x] + s[t] - v;
    if (blockIdx.x == 0 && t == 0) row_ptr[N] = Etot;
}

// pass 3: pos = row_ptr[dst] + rank[e]; atomic-free scattered store.
__global__ void scatter_kernel(const int* __restrict__ ei, int E, int N,
                               const int* __restrict__ row_ptr,
                               const int* __restrict__ rank,
                               int* __restrict__ csr_src) {
    const int Etot = E + N;
    const int T = gridDim.x * blockDim.x;
    int e = blockIdx.x * blockDim.x + threadIdx.x;
#pragma unroll 4
    for (int u = 0; u < 4; ++u, e += T) {
        if (e < Etot) {
            int src, dst;
            if (e < E) { src = ei[e]; dst = ei[E + e]; }
            else       { src = e - E; dst = e - E; }
            csr_src[row_ptr[dst] + rank[e]] = src;
        }
    }
}

// ---------------------------------------------------------------------------
// Layer-1 GEMM fused with count_rank (R22/R24-proven, 113us floor).
// gemm blocks [0,GGEMM): fp16 in/W, fdot2, fp16 out, fused alpha (ALPHA 1).
// count blocks [GGEMM,..): batched unroll-7 atomics.
// ---------------------------------------------------------------------------
__global__ __launch_bounds__(256) void gemm1_count_kernel(
        const __half* __restrict__ in,
        const __half* __restrict__ Wh,
        __half* __restrict__ out,
        const float* __restrict__ a_src,
        const float* __restrict__ a_dst,
        float* __restrict__ alpS,
        float* __restrict__ alpD,
        int N,
        const int* __restrict__ ei, int E,
        int* __restrict__ cnt, int* __restrict__ rank,
        int GGEMM) {
    constexpr int K4 = 32, CHUNK = 64, M = 64, RB = 8;
    __shared__ uint2 wlds[K4 * CHUNK];   // 16 KB

    if (blockIdx.x >= GGEMM) {
        const int Etot = E + N;
        const int T = (gridDim.x - GGEMM) * 256;
        int e = (blockIdx.x - GGEMM) * 256 + threadIdx.x;
#pragma unroll 7
        for (int u = 0; u < 7; ++u, e += T) {
            if (e < Etot) {
                int dst = (e < E) ? ei[E + e] : (e - E);   // self-loops appended
                rank[e] = atomicAdd(&cnt[dst], 1);
            }
        }
        return;
    }

    const unsigned short* wsrc = (const unsigned short*)Wh;
    for (int idx = threadIdx.x; idx < K4 * CHUNK; idx += 256) {
        int k4 = idx / CHUNK, c = idx % CHUNK;
        const unsigned short* wp = wsrc + (size_t)(4 * k4) * M + c;
        uint2 v;
        v.x = (unsigned int)wp[0]     | ((unsigned int)wp[M] << 16);
        v.y = (unsigned int)wp[2 * M] | ((unsigned int)wp[3 * M] << 16);
        wlds[idx] = v;
    }
    __syncthreads();

    const int wid  = threadIdx.x >> 6;
    const int lane = threadIdx.x & 63;
    const float aSv = a_src[lane];
    const float aDv = a_dst[lane];

    const int groups = (N + RB - 1) / RB;
    for (int g = blockIdx.x * 4 + wid; g < groups; g += GGEMM * 4) {
        const int n0 = g * RB;
        const bool full = (n0 + RB <= N);

        float acc[RB];
#pragma unroll
        for (int r = 0; r < RB; ++r) acc[r] = 0.0f;

        const uint2* xp = (const uint2*)(in + (size_t)n0 * 128);

        if (full) {
            uint2 xv[RB], xn[RB];
#pragma unroll
            for (int r = 0; r < RB; ++r) xv[r] = xp[r * K4];
#pragma unroll 2
            for (int k4 = 0; k4 < K4; ++k4) {
                if (k4 + 1 < K4) {
#pragma unroll
                    for (int r = 0; r < RB; ++r)
                        xn[r] = xp[r * K4 + k4 + 1];
                }
                uint2 wv = wlds[k4 * CHUNK + lane];
#pragma unroll
                for (int r = 0; r < RB; ++r) {
                    acc[r] = fdot2(as_h2(xv[r].x), as_h2(wv.x), acc[r]);
                    acc[r] = fdot2(as_h2(xv[r].y), as_h2(wv.y), acc[r]);
                }
                if (k4 + 1 < K4) {
#pragma unroll
                    for (int r = 0; r < RB; ++r) xv[r] = xn[r];
                }
            }
        } else {
#pragma unroll 1
            for (int k4 = 0; k4 < K4; ++k4) {
                uint2 wv = wlds[k4 * CHUNK + lane];
#pragma unroll 1
                for (int r = 0; r < RB; ++r) {
                    if (n0 + r >= N) break;
                    uint2 xr = xp[(size_t)r * K4 + k4];
                    acc[r] = fdot2(as_h2(xr.x), as_h2(wv.x), acc[r]);
                    acc[r] = fdot2(as_h2(xr.y), as_h2(wv.y), acc[r]);
                }
            }
        }

#pragma unroll
        for (int r = 0; r < RB; ++r) {
            if (!full && n0 + r >= N) break;
            const int n = n0 + r;
            out[(size_t)n * M + lane] = (__half)acc[r];

            float ps = acc[r] * aSv, pd = acc[r] * aDv;
            for (int mm = 16; mm >= 1; mm >>= 1) {
                ps += __shfl_xor(ps, mm, 64);
                pd += __shfl_xor(pd, mm, 64);
            }
            if ((lane & 31) == 0) {
                int idx = n * 2 + (lane >> 5);
                alpS[idx] = ps; alpD[idx] = pd;
            }
        }
    }
}

// ---------------------------------------------------------------------------
// Layer-2 GEMM via MFMA: [N][64] x [64][128] -> [N][128] fp16 + per-head
// alpha. 4 waves: rowgrp=wid>>1 (tile), colhalf=wid&1 (head, 64 cols).
// B in registers from WT2[128][64]. Alpha from MFMA acc: lane partial
// sum_t acc[t][i]*a[col(t)], reduced over 16-lane r-group, r==0 writes.
// Grid: ceil(NT/2) blocks, 2 tiles/block.
// ---------------------------------------------------------------------------
__global__ __launch_bounds__(256) void gemm2_mfma_kernel(
        const __half* __restrict__ in,    // [N][64]
        const __half* __restrict__ WT,    // [128][64] (transposed w2)
        __half* __restrict__ out,         // [N][128]
        const float* __restrict__ a_src,  // [128]
        const float* __restrict__ a_dst,  // [128]
        float* __restrict__ alpS,
        float* __restrict__ alpD,
        int N, int NT) {
    const int wid     = threadIdx.x >> 6;
    const int lane    = threadIdx.x & 63;
    const int rowgrp  = wid >> 1;
    const int colhalf = wid & 1;
    const int cb = colhalf * 64;
    const int r  = lane & 15;
    const int kg = lane >> 4;

    f16x8 bfrag[4][2];
#pragma unroll
    for (int t = 0; t < 4; ++t)
#pragma unroll
        for (int kf = 0; kf < 2; ++kf)
            bfrag[t][kf] = *(const f16x8*)(WT + (size_t)(cb + t * 16 + r) * 64 + kf * 32 + kg * 8);
    float asv[4], adv[4];
#pragma unroll
    for (int t = 0; t < 4; ++t) {
        asv[t] = a_src[cb + t * 16 + r];
        adv[t] = a_dst[cb + t * 16 + r];
    }

    const int rt = blockIdx.x * 2 + rowgrp;
    if (rt >= NT) return;
    const int n0 = rt * 16;

    f16x8 a0 = *(const f16x8*)(in + (size_t)(n0 + r) * 64 + kg * 8);
    f16x8 a1 = *(const f16x8*)(in + (size_t)(n0 + r) * 64 + 32 + kg * 8);

    f32x4 acc[4];
#pragma unroll
    for (int t = 0; t < 4; ++t) {
        acc[t] = (f32x4){0.0f, 0.0f, 0.0f, 0.0f};
        acc[t] = __builtin_amdgcn_mfma_f32_16x16x32_f16(a0, bfrag[t][0], acc[t], 0, 0, 0);
        acc[t] = __builtin_amdgcn_mfma_f32_16x16x32_f16(a1, bfrag[t][1], acc[t], 0, 0, 0);
    }

    // stores (D layout: col=cb+t*16+r, row=n0+kg*4+i)
#pragma unroll
    for (int i = 0; i < 4; ++i) {
        int grow = n0 + kg * 4 + i;
        if (grow < N) {
#pragma unroll
            for (int t = 0; t < 4; ++t)
                out[(size_t)grow * 128 + cb + t * 16 + r] = (__half)acc[t][i];
        }
    }
    // alpha: per-row sum over this head's 64 cols
    float ps[4], pd[4];
#pragma unroll
    for (int i = 0; i < 4; ++i) {
        ps[i] = acc[0][i] * asv[0] + acc[1][i] * asv[1] + acc[2][i] * asv[2] + acc[3][i] * asv[3];
        pd[i] = acc[0][i] * adv[0] + acc[1][i] * adv[1] + acc[2][i] * adv[2] + acc[3][i] * adv[3];
    }
    for (int mm = 8; mm >= 1; mm >>= 1) {
#pragma unroll
        for (int i = 0; i < 4; ++i) {
            ps[i] += __shfl_xor(ps[i], mm, 64);
            pd[i] += __shfl_xor(pd[i], mm, 64);
        }
    }
    if (r == 0) {
#pragma unroll
        for (int i = 0; i < 4; ++i) {
            int n = n0 + kg * 4 + i;
            if (n < N) {
                alpS[n * 2 + colhalf] = ps[i];
                alpD[n * 2 + colhalf] = pd[i];
            }
        }
    }
}

// ---------------------------------------------------------------------------
// Layer-3 GEMM via MFMA: [N][128] x [128][64] -> [N][64] fp16 + alpha (H1).
// Each wave owns all 64 cols, 4 tiles/block. B in registers (4x4 f16x8).
// ---------------------------------------------------------------------------
__global__ __launch_bounds__(256) void gemm3_mfma_kernel(
        const __half* __restrict__ in,    // [N][128]
        const __half* __restrict__ WT,    // [64][128] (transposed w3)
        __half* __restrict__ out,         // [N][64]
        const float* __restrict__ a_src,  // [64]
        const float* __restrict__ a_dst,  // [64]
        float* __restrict__ alpS,
        float* __restrict__ alpD,
        int N, int NT) {
    const int wid  = threadIdx.x >> 6;
    const int lane = threadIdx.x & 63;
    const int r  = lane & 15;
    const int kg = lane >> 4;

    f16x8 bfrag[4][4];
#pragma unroll
    for (int t = 0; t < 4; ++t)
#pragma unroll
        for (int kf = 0; kf < 4; ++kf)
            bfrag[t][kf] = *(const f16x8*)(WT + (size_t)(t * 16 + r) * 128 + kf * 32 + kg * 8);
    float asv[4], adv[4];
#pragma unroll
    for (int t = 0; t < 4; ++t) {
        asv[t] = a_src[t * 16 + r];
        adv[t] = a_dst[t * 16 + r];
    }

    const int rt = blockIdx.x * 4 + wid;
    if (rt >= NT) return;
    const int n0 = rt * 16;

    f16x8 a[4];
#pragma unroll
    for (int kf = 0; kf < 4; ++kf)
        a[kf] = *(const f16x8*)(in + (size_t)(n0 + r) * 128 + kf * 32 + kg * 8);

    f32x4 acc[4];
#pragma unroll
    for (int t = 0; t < 4; ++t) {
        acc[t] = (f32x4){0.0f, 0.0f, 0.0f, 0.0f};
#pragma unroll
        for (int kf = 0; kf < 4; ++kf)
            acc[t] = __builtin_amdgcn_mfma_f32_16x16x32_f16(a[kf], bfrag[t][kf], acc[t], 0, 0, 0);
    }

#pragma unroll
    for (int i = 0; i < 4; ++i) {
        int grow = n0 + kg * 4 + i;
        if (grow < N) {
#pragma unroll
            for (int t = 0; t < 4; ++t)
                out[(size_t)grow * 64 + t * 16 + r] = (__half)acc[t][i];
        }
    }
    float ps[4], pd[4];
#pragma unroll
    for (int i = 0; i < 4; ++i) {
        ps[i] = acc[0][i] * asv[0] + acc[1][i] * asv[1] + acc[2][i] * asv[2] + acc[3][i] * asv[3];
        pd[i] = acc[0][i] * adv[0] + acc[1][i] * adv[1] + acc[2][i] * adv[2] + acc[3][i] * adv[3];
    }
    for (int mm = 8; mm >= 1; mm >>= 1) {
#pragma unroll
        for (int i = 0; i < 4; ++i) {
            ps[i] += __shfl_xor(ps[i], mm, 64);
            pd[i] += __shfl_xor(pd[i], mm, 64);
        }
    }
    if (r == 0) {
#pragma unroll
        for (int i = 0; i < 4; ++i) {
            int n = n0 + kg * 4 + i;
            if (n < N) { alpS[n] = ps[i]; alpD[n] = pd[i]; }
        }
    }
}

// ---------------------------------------------------------------------------
// FC via MFMA (R21-proven): wave owns 64 cols, B fragments in registers from
// WT[512][64]; per 16-row tile: 2 x-loads + 8 MFMA + coalesced stores.
// ---------------------------------------------------------------------------
__global__ __launch_bounds__(256) void fcmfma_kernel(
        const __half* __restrict__ in,    // [N][64] fp16
        const __half* __restrict__ WT,    // [512][64] fp16 (transposed)
        const float* __restrict__ bias,   // [512]
        float* __restrict__ out,          // [N][512]
        int N, int NT) {
    const int wid  = threadIdx.x >> 6;
    const int lane = threadIdx.x & 63;
    const int cb = blockIdx.y * 256 + wid * 64;
    const int r  = lane & 15;
    const int kg = lane >> 4;

    f16x8 bfrag[4][2];
#pragma unroll
    for (int t = 0; t < 4; ++t)
#pragma unroll
        for (int kf = 0; kf < 2; ++kf)
            bfrag[t][kf] = *(const f16x8*)(WT + (size_t)(cb + t * 16 + r) * 64 + kf * 32 + kg * 8);
    float bs[4];
#pragma unroll
    for (int t = 0; t < 4; ++t) bs[t] = bias[cb + t * 16 + r];

    const int rt0 = blockIdx.x * 5;
#pragma unroll 1
    for (int q = 0; q < 5; ++q) {
        const int rt = rt0 + q;
        if (rt >= NT) break;
        const int n0 = rt * 16;
        f16x8 a0 = *(const f16x8*)(in + (size_t)(n0 + r) * 64 + kg * 8);
        f16x8 a1 = *(const f16x8*)(in + (size_t)(n0 + r) * 64 + 32 + kg * 8);
#pragma unroll
        for (int t = 0; t < 4; ++t) {
            f32x4 acc = {0.0f, 0.0f, 0.0f, 0.0f};
            acc = __builtin_amdgcn_mfma_f32_16x16x32_f16(a0, bfrag[t][0], acc, 0, 0, 0);
            acc = __builtin_amdgcn_mfma_f32_16x16x32_f16(a1, bfrag[t][1], acc, 0, 0, 0);
#pragma unroll
            for (int i = 0; i < 4; ++i) {
                int grow = n0 + kg * 4 + i;
                if (grow < N)
                    out[(size_t)grow * 512 + cb + t * 16 + r] = fmaxf(acc[i] + bs[t], 0.0f);
            }
        }
    }
}

// ---------------------------------------------------------------------------
// Aggregate (PL1 variants, layers 1+3): one wave per dst node, 64-edge
// chunks, two-phase; h gathered as FP16; softmax/accumulate fp32; fp16 out.
// ---------------------------------------------------------------------------
template <int H, int C>
__global__ __launch_bounds__(256) void aggregate_kernel(
        const __half* __restrict__ h,
        const float* __restrict__ alpha_s,
        const float* __restrict__ alpha_d,
        const int* __restrict__ row_ptr,
        const int* __restrict__ csr_src,
        const float* __restrict__ bias,
        __half* __restrict__ out, int N) {
    constexpr int M = H * C;
    __shared__ int   ss[4][64];
    __shared__ float sp[4][128];
    const int wid  = threadIdx.x >> 6;
    const int lane = threadIdx.x & 63;
    const int n = blockIdx.x * 4 + wid;
    if (n >= N) return;

    const int lo = row_ptr[n], hi = row_ptr[n + 1];
    const int myhead = (H == 2) ? (lane / C) : 0;

    float adv[H];
#pragma unroll
    for (int t = 0; t < H; ++t) adv[t] = alpha_d[n * H + t];

    float m[H], den[H], acc = 0.0f;
#pragma unroll
    for (int t = 0; t < H; ++t) { m[t] = -INFINITY; den[t] = 0.0f; }

    for (int e0 = lo; e0 < hi; e0 += 64) {
        const int idx = e0 + lane;
        const bool valid = idx < hi;
        const int src_l = csr_src[valid ? idx : hi - 1];

        // ---- phase A: lane-parallel logits ----
        float lg[H];
        if (H == 2) {
            float2 as = ((const float2*)alpha_s)[src_l];
            lg[0] = as.x + adv[0];
            lg[1] = as.y + adv[1];
        } else {
            lg[0] = alpha_s[src_l] + adv[0];
        }
#pragma unroll
        for (int t = 0; t < H; ++t) {
            float v = lg[t];
            v = v > 0.0f ? v : 0.2f * v;
            lg[t] = valid ? v : -INFINITY;
        }
        float cm[H];
#pragma unroll
        for (int t = 0; t < H; ++t) cm[t] = lg[t];
        for (int mm = 32; mm >= 1; mm >>= 1) {
#pragma unroll
            for (int t = 0; t < H; ++t)
                cm[t] = fmaxf(cm[t], __shfl_xor(cm[t], mm, 64));
        }
        float sc[H];
#pragma unroll
        for (int t = 0; t < H; ++t) {
            float mnew = fmaxf(m[t], cm[t]);
            sc[t] = __expf(m[t] - mnew);
            den[t] *= sc[t];
            m[t] = mnew;
        }
        acc *= (H == 1) ? sc[0] : (myhead == 0 ? sc[0] : sc[1]);

        float p[H], dsum[H];
#pragma unroll
        for (int t = 0; t < H; ++t) { p[t] = __expf(lg[t] - m[t]); dsum[t] = p[t]; }
        for (int mm = 32; mm >= 1; mm >>= 1) {
#pragma unroll
            for (int t = 0; t < H; ++t)
                dsum[t] += __shfl_xor(dsum[t], mm, 64);
        }
#pragma unroll
        for (int t = 0; t < H; ++t) den[t] += dsum[t];

        ss[wid][lane] = src_l;
        if (H == 2) ((float2*)sp[wid])[lane] = make_float2(p[0], p[1]);
        else        sp[wid][lane] = p[0];

        // ---- phase B: per-edge broadcast accumulate, 8-wide batch ----
        int nu = hi - e0; if (nu > 64) nu = 64;
        int u = 0;
#pragma unroll 1
        for (; u + 8 <= nu; u += 8) {
            int su[8];
#pragma unroll
            for (int t = 0; t < 8; ++t)
                su[t] = __builtin_amdgcn_readfirstlane(ss[wid][u + t]);
            float hv[8];
#pragma unroll
            for (int t = 0; t < 8; ++t)
                hv[t] = __half2float(h[(size_t)su[t] * M + lane]);
            if (H == 2) {
                const float2* pb = (const float2*)sp[wid];
#pragma unroll
                for (int t = 0; t < 8; ++t) {
                    float2 q = pb[u + t];
                    acc += (myhead == 0 ? q.x : q.y) * hv[t];
                }
            } else {
#pragma unroll
                for (int t = 0; t < 8; ++t)
                    acc += sp[wid][u + t] * hv[t];
            }
        }
#pragma unroll 1
        for (; u < nu; ++u) {
            int su = __builtin_amdgcn_readfirstlane(ss[wid][u]);
            float hv = __half2float(h[(size_t)su * M + lane]);
            if (H == 2) {
                float2 q = ((const float2*)sp[wid])[u];
                acc += (myhead == 0 ? q.x : q.y) * hv;
            } else {
                acc += sp[wid][u] * hv;
            }
        }
    }

    float dv = (H == 1) ? den[0] : (myhead == 0 ? den[0] : den[1]);
    float v = acc / dv + bias[lane];
    out[(size_t)n * M + lane] = (__half)fmaxf(v, 0.0f);
}

// ---------------------------------------------------------------------------
// Layer-2 aggregate, HEAD-SPLIT: 2 waves per node; h fp16 in, fp16 out.
// ---------------------------------------------------------------------------
__global__ __launch_bounds__(256) void aggregate2_kernel(
        const __half* __restrict__ h,       // [N][128] fp16
        const float* __restrict__ alpha_s,  // [N][2]
        const float* __restrict__ alpha_d,  // [N][2]
        const int* __restrict__ row_ptr,
        const int* __restrict__ csr_src,
        const float* __restrict__ bias,     // [128]
        __half* __restrict__ out, int N) {
    __shared__ int   ss[4][64];
    __shared__ float sp[4][64];
    const int wid  = threadIdx.x >> 6;
    const int lane = threadIdx.x & 63;
    const int gw   = blockIdx.x * 4 + wid;
    const int n    = gw >> 1;
    const int hd   = gw & 1;
    if (n >= N) return;

    const int lo = row_ptr[n], hi = row_ptr[n + 1];
    const float adv = alpha_d[n * 2 + hd];

    float m = -INFINITY, den = 0.0f, acc = 0.0f;

    for (int e0 = lo; e0 < hi; e0 += 64) {
        const int idx = e0 + lane;
        const bool valid = idx < hi;
        const int src_l = csr_src[valid ? idx : hi - 1];

        float lg = alpha_s[src_l * 2 + hd] + adv;
        lg = lg > 0.0f ? lg : 0.2f * lg;
        if (!valid) lg = -INFINITY;

        float cm = lg;
        for (int mm = 32; mm >= 1; mm >>= 1)
            cm = fmaxf(cm, __shfl_xor(cm, mm, 64));

        float mnew = fmaxf(m, cm);
        float sc = __expf(m - mnew);
        den *= sc; acc *= sc; m = mnew;

        float p = __expf(lg - m), ds = p;
        for (int mm = 32; mm >= 1; mm >>= 1)
            ds += __shfl_xor(ds, mm, 64);
        den += ds;

        ss[wid][lane] = src_l;
        sp[wid][lane] = p;

        int nu = hi - e0; if (nu > 64) nu = 64;
        int u = 0;
#pragma unroll 1
        for (; u + 8 <= nu; u += 8) {
            int su[8];
#pragma unroll
            for (int t = 0; t < 8; ++t)
                su[t] = __builtin_amdgcn_readfirstlane(ss[wid][u + t]);
            float hv[8];
#pragma unroll
            for (int t = 0; t < 8; ++t)
                hv[t] = __half2float(h[(size_t)su[t] * 128 + hd * 64 + lane]);
#pragma unroll
            for (int t = 0; t < 8; ++t)
                acc += sp[wid][u + t] * hv[t];
        }
#pragma unroll 1
        for (; u < nu; ++u) {
            int su = __builtin_amdgcn_readfirstlane(ss[wid][u]);
            acc += sp[wid][u] * __half2float(h[(size_t)su * 128 + hd * 64 + lane]);
        }
    }

    float v = acc / den + bias[hd * 64 + lane];
    out[(size_t)n * 128 + hd * 64 + lane] = (__half)fmaxf(v, 0.0f);
}

// ---------------------------------------------------------------------------

extern "C" void kernel_launch(void* const* d_in, const int* in_sizes, int n_in,
                              void* d_out, int out_size, void* d_ws, size_t ws_size,
                              hipStream_t stream) {
    const float* x   = (const float*)d_in[0];
    const int*   ei  = (const int*)  d_in[1];
    const float* w1  = (const float*)d_in[2];
    const float* as1 = (const float*)d_in[3];
    const float* ad1 = (const float*)d_in[4];
    const float* b1  = (const float*)d_in[5];
    const float* w2  = (const float*)d_in[6];
    const float* as2 = (const float*)d_in[7];
    const float* ad2 = (const float*)d_in[8];
    const float* b2  = (const float*)d_in[9];
    const float* w3  = (const float*)d_in[10];
    const float* as3 = (const float*)d_in[11];
    const float* ad3 = (const float*)d_in[12];
    const float* b3  = (const float*)d_in[13];
    const float* fcw = (const float*)d_in[14];
    const float* fcb = (const float*)d_in[15];
    float* out = (float*)d_out;

    const int N = in_sizes[0] / 128;
    const int E = in_sizes[1] / 2;
    const int Etot = E + N;

    // workspace carve-up (256B aligned regions)
    char* p = (char*)d_ws;
    auto alloc = [&](size_t bytes) {
        char* r = p;
        p += (bytes + 255) & ~(size_t)255;
        return r;
    };
    int*    cnt     = (int*)   alloc((size_t)N * 4);
    int*    row_ptr = (int*)   alloc((size_t)(N + 1) * 4);
    int*    rank    = (int*)   alloc((size_t)Etot * 4);
    int*    csr_src = (int*)   alloc((size_t)Etot * 4);
    int*    bsum    = (int*)   alloc((size_t)SCAN_NB * 4);
    int*    bbase   = (int*)   alloc((size_t)SCAN_NB * 4);
    __half* x16     = (__half*)alloc((size_t)N * 128 * 2);       // fp16 input x
    __half* bufA    = (__half*)alloc((size_t)(N + 16) * 128 * 2); // fp16 gemm out h (+pad)
    __half* bufB    = (__half*)alloc((size_t)(N + 16) * 128 * 2); // fp16 agg out (+pad)
    __half* bufC    = (__half*)alloc((size_t)(N + 16) * 64 * 2);  // fp16 agg3 out (FC in, +pad)
    __half* wh1     = (__half*)alloc((size_t)8192 * 2);          // linear [128][64]
    __half* wh2T    = (__half*)alloc((size_t)8192 * 2);          // [128][64] transposed
    __half* wh3T    = (__half*)alloc((size_t)8192 * 2);          // [64][128] transposed
    __half* fcwT    = (__half*)alloc((size_t)32768 * 2);         // [512][64] transposed
    float*  alpS    = (float*) alloc((size_t)N * 2 * 4);
    float*  alpD    = (float*) alloc((size_t)N * 2 * 4);
    (void)ws_size; (void)n_in; (void)out_size;

    // ---- cvt: x fp32->fp16 + weights (w2/w3/fcw transposed) ----
    hipMemsetAsync(cnt, 0, (size_t)N * 4, stream);
    const int n4 = N * 32;                      // float4 units in x
    const int XB = (n4 + 255) / 256;            // cvtx blocks
    const int WB = 224;                         // cvtw blocks
    cvt_kernel<<<XB + WB, 256, 0, stream>>>(
        x, x16, n4, w1, w2, w3, fcw, wh1, wh2T, wh3T, fcwT, XB);

    int gb  = (N + 3) / 4;        // aggregate (PL1): 4 waves/block, 1 node/wave
    int gb2 = (2 * N + 3) / 4;    // aggregate2: 2 waves/node
    const int GG1 = 1024;         // layer-1 gemm blocks
    const int GC1 = 1024;         // count blocks co-resident with gemm1
    const int NT  = (N + 15) / 16; // 16-row tiles (3125 exact at N=50000)

    // ---- layer 1 GEMM fused with count_rank ----
    gemm1_count_kernel<<<dim3(GG1 + GC1, 1), 256, 0, stream>>>(
        x16, wh1, bufA, as1, ad1, alpS, alpD, N, ei, E, cnt, rank, GG1);

    // ---- CSR: parallel scan + scatter ----
    scanA_kernel<<<SCAN_NB, 256, 0, stream>>>(cnt, N, bsum);
    scanB_kernel<<<1, 256, 0, stream>>>(bsum, bbase);
    scanC_kernel<<<SCAN_NB, 256, 0, stream>>>(cnt, N, Etot, bbase, row_ptr);
    const int CB = (Etot / 4 + 255) / 256 + 1;
    scatter_kernel<<<CB, 256, 0, stream>>>(ei, E, N, row_ptr, rank, csr_src);

    // ---- layer 1 aggregate ----
    aggregate_kernel<2, 32><<<gb, 256, 0, stream>>>(bufA, alpS, alpD, row_ptr, csr_src, b1, bufB, N);

    // ---- layer 2: MFMA GEMM (64->128) + head-split aggregate ----
    gemm2_mfma_kernel<<<(NT + 1) / 2, 256, 0, stream>>>(
        bufB, wh2T, bufA, as2, ad2, alpS, alpD, N, NT);
    aggregate2_kernel<<<gb2, 256, 0, stream>>>(bufA, alpS, alpD, row_ptr, csr_src, b2, bufB, N);

    // ---- layer 3: MFMA GEMM (128->64) + aggregate (fp16 out for FC) ----
    gemm3_mfma_kernel<<<(NT + 3) / 4, 256, 0, stream>>>(
        bufB, wh3T, bufA, as3, ad3, alpS, alpD, N, NT);
    aggregate_kernel<1, 64><<<gb, 256, 0, stream>>>(bufA, alpS, alpD, row_ptr, csr_src, b3, bufC, N);

    // ---- FC: 64 -> 512 + relu via MFMA, B-fragments in registers ----
    const int GX = (NT + 4) / 5;                // 5 tiles/block (625)
    fcmfma_kernel<<<dim3(GX, 2), 256, 0, stream>>>(
        bufC, fcwT, fcb, out, N, NT);
}